// Round 13
// baseline (133.099 us; speedup 1.0000x reference)
//
#include <hip/hip_runtime.h>
#include <hip/hip_bf16.h>

// B=16,S=4096,H=512 ; G=2,V=320,D=256 (Dg=128)
constexpr int BT = 65536;
constexpr int K  = 512;
constexpr int V  = 320;
constexpr int G  = 2;
constexpr int Dg = 128;
constexpr int MT = 128;          // rows per block (B-traffic lever: 640->320 MB vs MT=64)
constexpr int NSTEP = 8;         // K/64 (BK=64, as R12)
constexpr size_t WS_IMG = 4096;  // frag-ordered B img (640 KB)

using short8 = __attribute__((ext_vector_type(8))) short;
using f32x4  = __attribute__((ext_vector_type(4))) float;

static __device__ __forceinline__ unsigned short f2bf(float x) {
    unsigned u = __float_as_uint(x);
    unsigned r = 0x7FFFu + ((u >> 16) & 1u);   // RNE
    return (unsigned short)((u + r) >> 16);
}
static __device__ __forceinline__ unsigned pk2(float a, float b) {
    return (unsigned)f2bf(a) | ((unsigned)f2bf(b) << 16);
}
static __device__ __forceinline__ f32x4 mfma16(short8 a, short8 b, f32x4 c) {
    return __builtin_amdgcn_mfma_f32_16x16x32_bf16(a, b, c, 0, 0, 0);
}

// ---- prep: fragment-ordered bf16 B image (unchanged since R6) ----
// chunk index = (((g*16+t)*4+wc)*5+nt)*64+lane, 16 B each =
// bf16 of W[t*32+(lane>>4)*8 .. +7][g*320 + wc*80+nt*16+(lane&15)]
__global__ __launch_bounds__(256) void vq_prep(const float* __restrict__ Wm,
                                               unsigned char* __restrict__ img)
{
    int id   = blockIdx.x * 256 + threadIdx.x;   // 0..40959
    int lane = id & 63;
    int s    = id >> 6;
    int nt   = s % 5;
    int wcq  = (s / 5) & 3;
    int tk   = s / 20;         // g*16+t
    int g    = tk >> 4;
    int t    = tk & 15;
    int col  = g * V + wcq * 80 + nt * 16 + (lane & 15);
    int kb   = t * 32 + (lane >> 4) * 8;
    unsigned p[4];
#pragma unroll
    for (int jj = 0; jj < 4; ++jj)
        p[jj] = pk2(Wm[(size_t)(kb + 2 * jj) * 640 + col],
                    Wm[(size_t)(kb + 2 * jj + 1) * 640 + col]);
    *reinterpret_cast<uint4*>(img + (size_t)id * 16) = make_uint4(p[0], p[1], p[2], p[3]);
}

// ---- main: bf16 MFMA GEMM (128x320x512), BK=64, 8 waves = 2 rowh x 4 colq ----
// LDS 56KB: A [0,16K) swizzled [128 rows][64 k] bf16 ; B [16K,56K) two 20KB panels.
// grid 1024: g=(bid>>3)&1, rblk=(bid&7)|((bid>>4)<<3) (bid,bid+8 same XCD share hs).
// No launch_bounds min-arg (R2/R7 spill lesson). acc-80 is fine per R10 (VGPR 76).
__global__ __launch_bounds__(512) void vq_main(
    const float* __restrict__ hs, const unsigned char* __restrict__ img,
    const float* __restrict__ bv, const float* __restrict__ cbv,
    float* __restrict__ out, unsigned int* __restrict__ hist)
{
    __shared__ __align__(16) unsigned char smem[57344];

    const int tid  = threadIdx.x;
    const int bid  = blockIdx.x;
    const int g    = (bid >> 3) & 1;
    const int rblk = (bid & 7) | ((bid >> 4) << 3);
    const int r0   = rblk * MT;
    const int w    = tid >> 6;
    const int lane = tid & 63;
    const int l4   = lane & 15;
    const int lc   = lane >> 4;
    const int wc   = w & 3;        // col quarter (80 cols)
    const int h    = w >> 2;       // row half (64 rows)

    f32x4 acc[4][5] = {};

    // A staging: 2 slots/thread; slot = i*512+tid -> row = slot>>3, kq = slot&7 (8 floats)
    const int arow0 = tid >> 3,         akq0 = tid & 7;
    const int arow1 = (512 + tid) >> 3, akq1 = (512 + tid) & 7;
    const float* aptr0 = hs + (size_t)(r0 + arow0) * K + akq0 * 8;
    const float* aptr1 = hs + (size_t)(r0 + arow1) * K + akq1 * 8;
    const int awoff0 = (arow0 * 128 + akq0 * 16) ^ ((arow0 & 7) << 4);
    const int awoff1 = (arow1 * 128 + akq1 * 16) ^ ((arow1 & 7) << 4);
    // A frag read: row = h*64 + mt*16 + l4 (row&7 == l4&7), byte = row*128 + kk*64 + lc*16
    const int a_base = ((h * 64 + l4) * 128 + lc * 16) ^ ((l4 & 7) << 4);  // + mt*2048 + kk*64
    // B: linear double-panel copy (t = 2s, 2s+1); frag-ordered within each 20KB panel
    const unsigned char* bsrc = img + (size_t)g * 327680 + (size_t)tid * 16;
    const int b_rd = 16384 + wc * 5120 + lane * 16;   // + kk*20480 + nt*1024

    auto packA = [&](float4 x0, float4 y0, float4 x1, float4 y1) {
        *reinterpret_cast<uint4*>(&smem[awoff0]) =
            make_uint4(pk2(x0.x, x0.y), pk2(x0.z, x0.w), pk2(y0.x, y0.y), pk2(y0.z, y0.w));
        *reinterpret_cast<uint4*>(&smem[awoff1]) =
            make_uint4(pk2(x1.x, x1.y), pk2(x1.z, x1.w), pk2(y1.x, y1.y), pk2(y1.z, y1.w));
    };

    // prologue: A(0) in flight
    float4 ax0 = *reinterpret_cast<const float4*>(aptr0);
    float4 ay0 = *reinterpret_cast<const float4*>(aptr0 + 4);
    float4 ax1 = *reinterpret_cast<const float4*>(aptr1);
    float4 ay1 = *reinterpret_cast<const float4*>(aptr1 + 4);

    for (int s = 0; s < NSTEP; ++s) {
        // ---- stage: B double-panel (40KB) via LDS-DMA, A (16KB) convert+write ----
        const unsigned char* bs = bsrc + (size_t)s * 40960;
#pragma unroll
        for (int i = 0; i < 5; ++i)
            __builtin_amdgcn_global_load_lds(
                (const __attribute__((address_space(1))) void*)(bs + i * 8192),
                (__attribute__((address_space(3))) void*)(&smem[16384 + i * 8192 + tid * 16]),
                16, 0, 0);
        packA(ax0, ay0, ax1, ay1);        // auto-waits A(s) only
        __syncthreads();                  // drains B DMA + LDS writes
        // ---- compute; A(s+1) issued first so HBM latency hides under MFMA ----
        if (s + 1 < NSTEP) {
            ax0 = *reinterpret_cast<const float4*>(aptr0 + (s + 1) * 64);
            ay0 = *reinterpret_cast<const float4*>(aptr0 + (s + 1) * 64 + 4);
            ax1 = *reinterpret_cast<const float4*>(aptr1 + (s + 1) * 64);
            ay1 = *reinterpret_cast<const float4*>(aptr1 + (s + 1) * 64 + 4);
        }
#pragma unroll
        for (int kk = 0; kk < 2; ++kk) {          // t = 2s+kk (same t-order as R12)
            short8 av[4];
#pragma unroll
            for (int mt = 0; mt < 4; ++mt)
                av[mt] = *reinterpret_cast<const short8*>(
                    &smem[a_base + mt * 2048 + kk * 64]);
#pragma unroll
            for (int nt = 0; nt < 5; ++nt) {
                short8 bb = *reinterpret_cast<const short8*>(
                    &smem[b_rd + kk * 20480 + nt * 1024]);
#pragma unroll
                for (int mt = 0; mt < 4; ++mt)
                    acc[mt][nt] = mfma16(av[mt], bb, acc[mt][nt]);
            }
        }
        __syncthreads();                  // buffer reuse guard
    }

    // ---- epilogue: bias + argmax (D: col=l4, row=lc*4+reg within 16x16 tile) ----
    float biasv[5];
#pragma unroll
    for (int nt = 0; nt < 5; ++nt) biasv[nt] = bv[g * V + wc * 80 + nt * 16 + l4];

    float* red_v = reinterpret_cast<float*>(smem);          // [128][4]
    int*   red_i = reinterpret_cast<int*>(smem + 2048);     // [128][4]
    int*   idx_s = reinterpret_cast<int*>(smem + 4096);     // [128]

#pragma unroll
    for (int mt = 0; mt < 4; ++mt) {
#pragma unroll
        for (int reg = 0; reg < 4; ++reg) {
            float bestv = acc[mt][0][reg] + biasv[0];
            int   besti = wc * 80 + l4;
#pragma unroll
            for (int nt = 1; nt < 5; ++nt) {
                float v = acc[mt][nt][reg] + biasv[nt];
                int   ci = wc * 80 + nt * 16 + l4;
                if (v > bestv) { bestv = v; besti = ci; }
            }
#pragma unroll
            for (int m = 1; m < 16; m <<= 1) {   // reduce across the 16 l4-lanes of this row
                float ov = __shfl_xor(bestv, m);
                int   oi = __shfl_xor(besti, m);
                if (ov > bestv || (ov == bestv && oi < besti)) { bestv = ov; besti = oi; }
            }
            if (l4 == 0) {
                int row = h * 64 + mt * 16 + lc * 4 + reg;
                red_v[row * 4 + wc] = bestv;
                red_i[row * 4 + wc] = besti;
            }
        }
    }
    __syncthreads();

    if (tid < MT) {
        float bb = red_v[tid * 4]; int bi = red_i[tid * 4];
#pragma unroll
        for (int c = 1; c < 4; ++c) {
            float v = red_v[tid * 4 + c]; int ii = red_i[tid * 4 + c];
            if (v > bb || (v == bb && ii < bi)) { bb = v; bi = ii; }
        }
        idx_s[tid] = bi;
        atomicAdd(&hist[g * V + bi], 1u);
    }
    __syncthreads();

    // ---- gather: 128 rows x 32 float4 = 4096 chunks, 8 per thread ----
#pragma unroll
    for (int i = 0; i < 8; ++i) {
        int idx = i * 512 + tid;
        int row = idx >> 5;
        int d4  = idx & 31;
        int vi  = idx_s[row];
        float4 val = *reinterpret_cast<const float4*>(&cbv[((size_t)(g * V + vi)) * Dg + d4 * 4]);
        *reinterpret_cast<float4*>(&out[((size_t)(r0 + row)) * (G * Dg) + g * Dg + d4 * 4]) = val;
    }
}

// Perplexity from histogram: one wave.
__global__ void vq_ppl(const unsigned int* __restrict__ hist, float* __restrict__ outp)
{
    int lane = threadIdx.x;  // 64
    float ppl = 0.0f;
    for (int g = 0; g < G; ++g) {
        float local = 0.0f;
        for (int v = lane; v < V; v += 64) {
            float m = (float)hist[g * V + v] * (1.0f / (float)BT);
            local += m * logf(m + 1e-7f);
        }
#pragma unroll
        for (int off = 32; off; off >>= 1) local += __shfl_down(local, off);
        if (lane == 0) ppl += expf(-local);
    }
    if (lane == 0) outp[0] = ppl;
}

extern "C" void kernel_launch(void* const* d_in, const int* in_sizes, int n_in,
                              void* d_out, int out_size, void* d_ws, size_t ws_size,
                              hipStream_t stream)
{
    const float* hs  = (const float*)d_in[0];   // (65536, 512)
    const float* Wm  = (const float*)d_in[1];   // (512, 640)
    const float* bv  = (const float*)d_in[2];   // (640,)
    const float* cbv = (const float*)d_in[3];   // (640, 128)
    float* out = (float*)d_out;                 // 65536*256 floats + 1 float perplexity

    unsigned int*  hist = (unsigned int*)d_ws;
    unsigned char* img  = (unsigned char*)d_ws + WS_IMG;

    hipMemsetAsync(d_ws, 0, G * V * sizeof(unsigned int), stream);
    vq_prep<<<160, 256, 0, stream>>>(Wm, img);
    vq_main<<<1024, 512, 0, stream>>>(hs, img, bv, cbv, out, hist);
    vq_ppl<<<1, 64, 0, stream>>>(hist, out + (size_t)BT * G * Dg);
}